// Round 7
// baseline (132.932 us; speedup 1.0000x reference)
//
#include <hip/hip_runtime.h>
#include <hip/hip_bf16.h>

#define A_DIM 200
#define F_DIM 53
#define NAF 38
#define NPHYS 15
#define R_OUT 20
#define C_OUT 1024
#define BLOCK 512
#define NW 8         // waves per block
#define HPAD 40      // s_hb ushort row stride: cols 0..31 = atom k0..31 (later h),
                     // cols 32..39 = atom k32..37 (+2 zero pad), never overwritten
#define MROWS 208
#define KP 24        // wcT k-stride (k>=20 zeroed)

typedef __attribute__((ext_vector_type(8))) short short8;
typedef __attribute__((ext_vector_type(4))) float floatx4;

__device__ __forceinline__ float bf2f(ushort u) { return __uint_as_float((uint)u << 16); }
__device__ __forceinline__ ushort f2bf(float f) {
    union { __hip_bfloat16 h; ushort u; } cv; cv.h = __float2bfloat16(f); return cv.u;
}

// Wc (20,1024) fp32 -> wcT (1024,24) bf16, k>=20 zeroed
__global__ void wc_prep(const float* __restrict__ Wc, ushort* __restrict__ wcT) {
    const int i = blockIdx.x * 256 + threadIdx.x;
    if (i >= C_OUT * KP) return;
    const int col = i / KP, k = i - col * KP;
    wcT[i] = f2bf((k < R_OUT) ? Wc[k * C_OUT + col] : 0.f);
}

template <bool USE_WS>
__global__ __launch_bounds__(BLOCK, 6) void pggcn_kernel(
    const float* __restrict__ inputs,
    const int*   __restrict__ i_s,
    const float* __restrict__ W_self,
    const float* __restrict__ W_nei,
    const float* __restrict__ b_r,
    const float* __restrict__ Wc,
    const float* __restrict__ bc,
    const float* __restrict__ W1,
    const float* __restrict__ b1,
    const float* __restrict__ W5,
    const float* __restrict__ b5,
    const float* __restrict__ W6,
    const float* __restrict__ b6,
    const float* __restrict__ W7,
    const float* __restrict__ b7,
    const ushort* __restrict__ wcT,
    float* __restrict__ out)
{
    __shared__ __align__(16) ushort s_hb[MROWS * HPAD];   // 16640 B
    __shared__ float s_aggp[12 * 40];                     // 1920 B
    __shared__ float s_agg[40];
    __shared__ float s_hnei[32];                          // 20 valid, 20..31 = 0
    __shared__ float s_phys[NPHYS];

    // aliases into s_hb (dead after main loop)
    float* s_pool = (float*)s_hb;                    // 1024 f
    float* s_red  = (float*)s_hb + C_OUT;            // 16*32 f
    float* s_d1   = (float*)s_hb + C_OUT + 512;      // 32 f
    float* s_d5   = (float*)s_hb + C_OUT + 544;      // 16 f

    const int b    = blockIdx.x;
    const int t    = threadIdx.x;
    const int lane = t & 63;
    const int wv   = t >> 6;        // 0..7
    const int lr   = lane & 15;
    const int lg   = lane >> 4;
    const int ns   = i_s[b];
    const int nmt  = (ns + 15) >> 4;
    const float* in_b = inputs + (size_t)b * (A_DIM * F_DIM);

    // ---- W_self B-frags (2 n-tiles x 2 k-steps); B layout col=lane&15,
    //      k=(lane>>4)*8+j ----
    short8 bws0[2], bws1[2];
    #pragma unroll
    for (int nt = 0; nt < 2; ++nt) {
        const int c = nt * 16 + lr;
        const bool cv_ = (c < R_OUT);
        #pragma unroll
        for (int j = 0; j < 8; ++j) {
            const int k0 = lg * 8 + j;        // 0..31 (< NAF)
            const int k1 = 32 + lg * 8 + j;   // 32..39
            bws0[nt][j] = (short)(cv_ ? f2bf(W_self[k0 * R_OUT + c]) : 0);
            bws1[nt][j] = (short)((cv_ && k1 < NAF) ? f2bf(W_self[k1 * R_OUT + c]) : 0);
        }
    }

    // physics out early (overlaps everything)
    if (t < NPHYS) {
        const float p = in_b[NAF + t];
        s_phys[t] = p;
        out[(size_t)b * 16 + 1 + t] = p;
    }

    // ---- stage atoms bf16: 40 cols/row; f>=NAF and rows>=ns zeroed ----
    const int tot = nmt * 16 * HPAD;
    for (int i = t; i < tot; i += BLOCK) {
        const int r = i / HPAD;
        const int f = i - r * HPAD;
        const float v = (r < ns && f < NAF) ? in_b[r * F_DIM + f] : 0.f;
        s_hb[i] = f2bf(v);
    }
    __syncthreads();

    // ---- agg partials: 12 row-groups x 40 cols (480 threads) ----
    if (t < 480) {
        const int f = t % 40, g = t / 40;
        float s = 0.f;
        for (int r = g; r < ns; r += 12) s += bf2f(s_hb[r * HPAD + f]);
        s_aggp[g * 40 + f] = s;
    }
    __syncthreads();

    if (t < 40) {
        float s = 0.f;
        #pragma unroll
        for (int g = 0; g < 12; ++g) s += s_aggp[g * 40 + t];
        s_agg[t] = s;
    }
    __syncthreads();

    // ---- hnei = b_r + agg @ W_nei (fp32 exact); cols 20..31 = 0 ----
    if (t < 32) {
        float s = 0.f;
        if (t < R_OUT) {
            s = b_r[t];
            #pragma unroll
            for (int f = 0; f < NAF; ++f) s += s_agg[f] * W_nei[f * R_OUT + t];
        }
        s_hnei[t] = s;
    }
    __syncthreads();

    // ---- h-MFMA in place: h = (row<ns) ? relu(atom@W_self + hnei) : 0 ----
    for (int mt = wv; mt < nmt; mt += NW) {
        const int ar = mt * 16 + lr;
        const short8 a0 = *(const short8*)&s_hb[ar * HPAD + lg * 8];
        short8 a1 = short8{0, 0, 0, 0, 0, 0, 0, 0};
        if (lg == 0) a1 = *(const short8*)&s_hb[ar * HPAD + 32];
        const float hn0 = s_hnei[lr];
        const float hn1 = s_hnei[16 + lr];
        floatx4 aS0 = {hn0, hn0, hn0, hn0};
        floatx4 aS1 = {hn1, hn1, hn1, hn1};
        aS0 = __builtin_amdgcn_mfma_f32_16x16x32_bf16(a0, bws0[0], aS0, 0, 0, 0);
        aS0 = __builtin_amdgcn_mfma_f32_16x16x32_bf16(a1, bws1[0], aS0, 0, 0, 0);
        aS1 = __builtin_amdgcn_mfma_f32_16x16x32_bf16(a0, bws0[1], aS1, 0, 0, 0);
        aS1 = __builtin_amdgcn_mfma_f32_16x16x32_bf16(a1, bws1[1], aS1, 0, 0, 0);
        // C/D layout: col = lane&15, row = (lane>>4)*4 + q
        #pragma unroll
        for (int q = 0; q < 4; ++q) {
            const int row = mt * 16 + lg * 4 + q;
            const bool v = (row < ns);
            s_hb[row * HPAD + lr]      = v ? f2bf(fmaxf(aS0[q], 0.f)) : (ushort)0;
            s_hb[row * HPAD + 16 + lr] = v ? f2bf(fmaxf(aS1[q], 0.f)) : (ushort)0;
        }
    }

    // ---- main B-frags (8 n-tiles/wave) — loads fly while waiting at barrier ----
    short8 bfr[8];
    float  bcv[8];
    #pragma unroll
    for (int nt = 0; nt < 8; ++nt) {
        const int col = wv * 128 + nt * 16 + lr;
        bcv[nt] = bc[col];
        if (USE_WS) {
            if (lg < 3) bfr[nt] = *(const short8*)&wcT[col * KP + lg * 8];
            else        bfr[nt] = short8{0, 0, 0, 0, 0, 0, 0, 0};
        } else {
            #pragma unroll
            for (int j = 0; j < 8; ++j) {
                const int k = lg * 8 + j;
                bfr[nt][j] = (short)((k < R_OUT) ? f2bf(Wc[k * C_OUT + col]) : 0);
            }
        }
    }
    __syncthreads();

    // ---- main: pooled = sum_rows relu(h @ Wc + bc); dead rows corrected ----
    float pool[8];
    #pragma unroll
    for (int nt = 0; nt < 8; ++nt) pool[nt] = 0.f;

    for (int mt = 0; mt < nmt; ++mt) {
        const short8 af = *(const short8*)&s_hb[(mt * 16 + lr) * HPAD + lg * 8];
        #pragma unroll
        for (int nt = 0; nt < 8; ++nt) {
            floatx4 acc = { bcv[nt], bcv[nt], bcv[nt], bcv[nt] };
            acc = __builtin_amdgcn_mfma_f32_16x16x32_bf16(af, bfr[nt], acc, 0, 0, 0);
            pool[nt] += fmaxf(acc[0], 0.f) + fmaxf(acc[1], 0.f)
                      + fmaxf(acc[2], 0.f) + fmaxf(acc[3], 0.f);
        }
    }
    const float dead = (float)(nmt * 16 - ns);
    if (lg == 0) {
        #pragma unroll
        for (int nt = 0; nt < 8; ++nt) pool[nt] -= dead * fmaxf(bcv[nt], 0.f);
    }
    #pragma unroll
    for (int nt = 0; nt < 8; ++nt) {
        float p = pool[nt];
        p += __shfl_xor(p, 16);
        p += __shfl_xor(p, 32);
        pool[nt] = p;
    }
    __syncthreads();   // all s_hb reads done; alias region safe
    if (lg == 0) {
        #pragma unroll
        for (int nt = 0; nt < 8; ++nt) s_pool[wv * 128 + nt * 16 + lr] = pool[nt];
    }
    __syncthreads();

    // ---- d1 partials: 16 parts x 64 j ----
    {
        const int m = t & 31, part = t >> 5;
        const int j0 = part * 64;
        float s = 0.f;
        for (int j = j0; j < j0 + 64; ++j) s += s_pool[j] * W1[j * 32 + m];
        s_red[part * 32 + m] = s;
    }
    __syncthreads();
    if (t < 32) {
        float s = b1[t];
        #pragma unroll
        for (int p = 0; p < 16; ++p) s += s_red[p * 32 + t];
        s_d1[t] = fmaxf(s, 0.f);
    }
    __syncthreads();

    // ---- d5 = relu(d1 @ W5 + b5) ----
    if (t < 16) {
        float s = b5[t];
        #pragma unroll
        for (int m = 0; m < 32; ++m) s += s_d1[m] * W5[m * 16 + t];
        s_d5[t] = fmaxf(s, 0.f);
    }
    __syncthreads();

    // ---- model_var, merge, output ----
    if (t == 0) {
        float mv = b6[0];
        #pragma unroll
        for (int m = 0; m < 16; ++m) mv += s_d5[m] * W6[m];
        float o = b7[0] + W7[0] * mv;
        #pragma unroll
        for (int i = 0; i < NPHYS; ++i) o += W7[i + 1] * s_phys[i];
        out[(size_t)b * 16] = o;
    }
}

extern "C" void kernel_launch(void* const* d_in, const int* in_sizes, int n_in,
                              void* d_out, int out_size, void* d_ws, size_t ws_size,
                              hipStream_t stream) {
    const float* inputs = (const float*)d_in[0];
    const int*   i_s    = (const int*)d_in[1];
    const float* W_self = (const float*)d_in[2];
    const float* W_nei  = (const float*)d_in[3];
    const float* b_r    = (const float*)d_in[4];
    const float* Wc     = (const float*)d_in[5];
    const float* bc     = (const float*)d_in[6];
    const float* W1     = (const float*)d_in[7];
    const float* b1     = (const float*)d_in[8];
    const float* W5     = (const float*)d_in[9];
    const float* b5     = (const float*)d_in[10];
    const float* W6     = (const float*)d_in[11];
    const float* b6     = (const float*)d_in[12];
    const float* W7     = (const float*)d_in[13];
    const float* b7     = (const float*)d_in[14];
    float* out = (float*)d_out;

    const int B = in_sizes[1];   // 1024
    const bool use_ws = (ws_size >= (size_t)(C_OUT * KP * sizeof(ushort)));
    ushort* wcT = (ushort*)d_ws;

    if (use_ws) {
        wc_prep<<<(C_OUT * KP + 255) / 256, 256, 0, stream>>>(Wc, wcT);
        pggcn_kernel<true><<<B, BLOCK, 0, stream>>>(inputs, i_s, W_self, W_nei, b_r,
            Wc, bc, W1, b1, W5, b5, W6, b6, W7, b7, wcT, out);
    } else {
        pggcn_kernel<false><<<B, BLOCK, 0, stream>>>(inputs, i_s, W_self, W_nei, b_r,
            Wc, bc, W1, b1, W5, b5, W6, b6, W7, b7, wcT, out);
    }
}

// Round 8
// 70.948 us; speedup vs baseline: 1.8736x; 1.8736x over previous
//
#include <hip/hip_runtime.h>
#include <hip/hip_bf16.h>

#define A_DIM 200
#define F_DIM 53
#define NAF 38
#define NPHYS 15
#define R_OUT 20
#define C_OUT 1024
#define BLOCK 256
#define NW 4         // waves per block
#define HPAD 40      // s_hb ushort row stride: cols 0..31 atom k0..31 (later h),
                     // cols 32..39 atom k32..37 (+2 zero), never overwritten
#define MROWS 208
#define KP 24        // wcT k-stride (k>=20 zeroed)

typedef __attribute__((ext_vector_type(8))) short short8;
typedef __attribute__((ext_vector_type(4))) float floatx4;

__device__ __forceinline__ float bf2f(ushort u) { return __uint_as_float((uint)u << 16); }
__device__ __forceinline__ ushort f2bf(float f) {
    union { __hip_bfloat16 h; ushort u; } cv; cv.h = __float2bfloat16(f); return cv.u;
}

// Wc (20,1024) fp32 -> wcT (1024,24) bf16, k>=20 zeroed
__global__ void wc_prep(const float* __restrict__ Wc, ushort* __restrict__ wcT) {
    const int i = blockIdx.x * 256 + threadIdx.x;
    if (i >= C_OUT * KP) return;
    const int col = i / KP, k = i - col * KP;
    wcT[i] = f2bf((k < R_OUT) ? Wc[k * C_OUT + col] : 0.f);
}

// SPLIT=1: grid 2B, block (b, half) computes pooled for 512 cols and writes
//          pre-bias d1 partial (32 floats) to d1p[b*64 + half*32 + m].
// SPLIT=0: grid B, full per-block pipeline incl. d1/d5/out (fallback).
template <bool USE_WS, bool SPLIT>
__global__ __launch_bounds__(BLOCK, SPLIT ? 8 : 4) void pggcn_kernel(
    const float* __restrict__ inputs,
    const int*   __restrict__ i_s,
    const float* __restrict__ W_self,
    const float* __restrict__ W_nei,
    const float* __restrict__ b_r,
    const float* __restrict__ Wc,
    const float* __restrict__ bc,
    const float* __restrict__ W1,
    const float* __restrict__ b1,
    const float* __restrict__ W5,
    const float* __restrict__ b5,
    const float* __restrict__ W6,
    const float* __restrict__ b6,
    const float* __restrict__ W7,
    const float* __restrict__ b7,
    const ushort* __restrict__ wcT,
    float* __restrict__ d1p,
    float* __restrict__ out)
{
    __shared__ __align__(16) ushort s_hb[MROWS * HPAD];   // 16640 B
    __shared__ float s_aggp[6 * 40];                      // 960 B
    __shared__ float s_agg[40];
    __shared__ float s_hnei[32];                          // 20 valid, 20..31 = 0
    __shared__ float s_phys[NPHYS];

    // aliases into s_hb (dead after main loop)
    float* s_pool = (float*)s_hb;                         // 512 (split) / 1024
    float* s_red  = (float*)s_hb + (SPLIT ? 512 : 1024);  // 8*32
    float* s_d1   = s_red + 256;                          // 32 (fallback only)
    float* s_d5   = s_d1 + 32;                            // 16 (fallback only)

    const int bx    = blockIdx.x;
    const int b     = SPLIT ? (bx >> 1) : bx;
    const int half0 = SPLIT ? (bx & 1) : 0;
    const int t     = threadIdx.x;
    const int lane  = t & 63;
    const int wv    = t >> 6;        // 0..3
    const int lr    = lane & 15;
    const int lg    = lane >> 4;
    const int ns    = i_s[b];
    const int nmt   = (ns + 15) >> 4;
    const float* in_b = inputs + (size_t)b * (A_DIM * F_DIM);

    // ---- W_self B-frags (2 n-tiles x 2 k-steps); col=lane&15, k=(lane>>4)*8+j ----
    short8 bws0[2], bws1[2];
    #pragma unroll
    for (int nt = 0; nt < 2; ++nt) {
        const int c = nt * 16 + lr;
        const bool cv_ = (c < R_OUT);
        #pragma unroll
        for (int j = 0; j < 8; ++j) {
            const int k0 = lg * 8 + j;        // 0..31 (< NAF)
            const int k1 = 32 + lg * 8 + j;   // 32..63
            bws0[nt][j] = (short)(cv_ ? f2bf(W_self[k0 * R_OUT + c]) : 0);
            bws1[nt][j] = (short)((cv_ && k1 < NAF) ? f2bf(W_self[k1 * R_OUT + c]) : 0);
        }
    }

    // physics out early (half 0 owns it); fallback also stages to LDS
    if ((!SPLIT || half0 == 0) && t < NPHYS) {
        const float p = in_b[NAF + t];
        if (!SPLIT) s_phys[t] = p;
        out[(size_t)b * 16 + 1 + t] = p;
    }

    // ---- stage atoms bf16: 40 cols/row; f>=NAF and rows>=ns zeroed ----
    const int tot = nmt * 16 * HPAD;
    for (int i = t; i < tot; i += BLOCK) {
        const int r = i / HPAD;
        const int f = i - r * HPAD;
        const float v = (r < ns && f < NAF) ? in_b[r * F_DIM + f] : 0.f;
        s_hb[i] = f2bf(v);
    }
    __syncthreads();

    // ---- agg partials: 6 row-groups x 40 cols (240 threads) ----
    if (t < 240) {
        const int f = t % 40, g = t / 40;
        float s = 0.f;
        for (int r = g; r < ns; r += 6) s += bf2f(s_hb[r * HPAD + f]);
        s_aggp[g * 40 + f] = s;
    }
    __syncthreads();
    if (t < 40) {
        float s = 0.f;
        #pragma unroll
        for (int g = 0; g < 6; ++g) s += s_aggp[g * 40 + t];
        s_agg[t] = s;
    }
    __syncthreads();

    // ---- hnei = b_r + agg @ W_nei (fp32 exact); cols 20..31 = 0 ----
    if (t < 32) {
        float s = 0.f;
        if (t < R_OUT) {
            s = b_r[t];
            #pragma unroll
            for (int f = 0; f < NAF; ++f) s += s_agg[f] * W_nei[f * R_OUT + t];
        }
        s_hnei[t] = s;
    }
    __syncthreads();

    // ---- h-MFMA in place: h = (row<ns) ? relu(atom@W_self + hnei) : 0 ----
    for (int mt = wv; mt < nmt; mt += NW) {
        const int ar = mt * 16 + lr;
        const short8 a0 = *(const short8*)&s_hb[ar * HPAD + lg * 8];
        short8 a1 = short8{0, 0, 0, 0, 0, 0, 0, 0};
        if (lg == 0) a1 = *(const short8*)&s_hb[ar * HPAD + 32];
        const float hn0 = s_hnei[lr];
        const float hn1 = s_hnei[16 + lr];
        floatx4 aS0 = {hn0, hn0, hn0, hn0};
        floatx4 aS1 = {hn1, hn1, hn1, hn1};
        aS0 = __builtin_amdgcn_mfma_f32_16x16x32_bf16(a0, bws0[0], aS0, 0, 0, 0);
        aS0 = __builtin_amdgcn_mfma_f32_16x16x32_bf16(a1, bws1[0], aS0, 0, 0, 0);
        aS1 = __builtin_amdgcn_mfma_f32_16x16x32_bf16(a0, bws0[1], aS1, 0, 0, 0);
        aS1 = __builtin_amdgcn_mfma_f32_16x16x32_bf16(a1, bws1[1], aS1, 0, 0, 0);
        // C/D layout: col = lane&15, row = (lane>>4)*4 + q
        #pragma unroll
        for (int q = 0; q < 4; ++q) {
            const int row = mt * 16 + lg * 4 + q;
            const bool v = (row < ns);
            s_hb[row * HPAD + lr]      = v ? f2bf(fmaxf(aS0[q], 0.f)) : (ushort)0;
            s_hb[row * HPAD + 16 + lr] = v ? f2bf(fmaxf(aS1[q], 0.f)) : (ushort)0;
        }
    }

    // ---- main: pooled = sum_rows relu(h @ Wc + bc), NQ quarters of 4 tiles ----
    constexpr int NQ = SPLIT ? 2 : 4;
    const float dead = (float)(nmt * 16 - ns);
    float pool[NQ * 4];
    #pragma unroll
    for (int i = 0; i < NQ * 4; ++i) pool[i] = 0.f;

    #pragma unroll 1
    for (int qt = 0; qt < NQ; ++qt) {
        short8 bfr[4];
        float  bcv[4];
        #pragma unroll
        for (int nt = 0; nt < 4; ++nt) {
            const int col = half0 * 512 + wv * (SPLIT ? 128 : 256) + qt * 64 + nt * 16 + lr;
            bcv[nt] = bc[col];
            if (USE_WS) {
                if (lg < 3) bfr[nt] = *(const short8*)&wcT[col * KP + lg * 8];
                else        bfr[nt] = short8{0, 0, 0, 0, 0, 0, 0, 0};
            } else {
                #pragma unroll
                for (int j = 0; j < 8; ++j) {
                    const int k = lg * 8 + j;
                    bfr[nt][j] = (short)((k < R_OUT) ? f2bf(Wc[k * C_OUT + col]) : 0);
                }
            }
        }
        if (qt == 0) __syncthreads();   // h ready; frag-load latency overlapped

        for (int mt = 0; mt < nmt; ++mt) {
            const short8 af = *(const short8*)&s_hb[(mt * 16 + lr) * HPAD + lg * 8];
            #pragma unroll
            for (int nt = 0; nt < 4; ++nt) {
                floatx4 acc = { bcv[nt], bcv[nt], bcv[nt], bcv[nt] };
                acc = __builtin_amdgcn_mfma_f32_16x16x32_bf16(af, bfr[nt], acc, 0, 0, 0);
                pool[qt * 4 + nt] += fmaxf(acc[0], 0.f) + fmaxf(acc[1], 0.f)
                                   + fmaxf(acc[2], 0.f) + fmaxf(acc[3], 0.f);
            }
        }
        // exact dead-row correction (rows >= ns contributed relu(bc))
        if (lg == 0) {
            #pragma unroll
            for (int nt = 0; nt < 4; ++nt)
                pool[qt * 4 + nt] -= dead * fmaxf(bcv[nt], 0.f);
        }
    }

    #pragma unroll
    for (int i = 0; i < NQ * 4; ++i) {
        float p = pool[i];
        p += __shfl_xor(p, 16);
        p += __shfl_xor(p, 32);
        pool[i] = p;
    }
    __syncthreads();   // all s_hb reads done; alias region safe
    if (lg == 0) {
        #pragma unroll
        for (int qt = 0; qt < NQ; ++qt)
            #pragma unroll
            for (int nt = 0; nt < 4; ++nt)
                s_pool[wv * (SPLIT ? 128 : 256) + qt * 64 + nt * 16 + lr] = pool[qt * 4 + nt];
    }
    __syncthreads();

    if (SPLIT) {
        // ---- pre-bias d1 partial over this half's 512 cols: 8 parts x 64 ----
        {
            const int m = t & 31, part = t >> 5;
            const int j0 = part * 64;
            float s = 0.f;
            for (int jl = j0; jl < j0 + 64; ++jl)
                s += s_pool[jl] * W1[(half0 * 512 + jl) * 32 + m];
            s_red[part * 32 + m] = s;
        }
        __syncthreads();
        if (t < 32) {
            float s = 0.f;
            #pragma unroll
            for (int p = 0; p < 8; ++p) s += s_red[p * 32 + t];
            d1p[(size_t)b * 64 + half0 * 32 + t] = s;
        }
    } else {
        // ---- fallback: full d1/d5/out in-block ----
        {
            const int m = t & 31, part = t >> 5;
            const int j0 = part * 128;
            float s = 0.f;
            for (int j = j0; j < j0 + 128; ++j) s += s_pool[j] * W1[j * 32 + m];
            s_red[part * 32 + m] = s;
        }
        __syncthreads();
        if (t < 32) {
            float s = b1[t];
            #pragma unroll
            for (int p = 0; p < 8; ++p) s += s_red[p * 32 + t];
            s_d1[t] = fmaxf(s, 0.f);
        }
        __syncthreads();
        if (t < 16) {
            float s = b5[t];
            #pragma unroll
            for (int m = 0; m < 32; ++m) s += s_d1[m] * W5[m * 16 + t];
            s_d5[t] = fmaxf(s, 0.f);
        }
        __syncthreads();
        if (t == 0) {
            float mv = b6[0];
            #pragma unroll
            for (int m = 0; m < 16; ++m) mv += s_d5[m] * W6[m];
            float o = b7[0] + W7[0] * mv;
            #pragma unroll
            for (int i = 0; i < NPHYS; ++i) o += W7[i + 1] * s_phys[i];
            out[(size_t)b * 16] = o;
        }
    }
}

// combine: d1 = relu(p0 + p1 + b1); d5 = relu(d1@W5 + b5); out0 = merge.
// 16 threads per batch element, 16 elements per block.
__global__ void pggcn_combine(
    const float* __restrict__ inputs,
    const float* __restrict__ d1p,
    const float* __restrict__ b1,
    const float* __restrict__ W5,
    const float* __restrict__ b5,
    const float* __restrict__ W6,
    const float* __restrict__ b6,
    const float* __restrict__ W7,
    const float* __restrict__ b7,
    float* __restrict__ out, int B)
{
    const int t = threadIdx.x;
    const int g = t >> 4, dim = t & 15;
    const int b = blockIdx.x * 16 + g;
    if (b >= B) return;
    const float* wsd = d1p + (size_t)b * 64;
    float s = b5[dim];
    #pragma unroll
    for (int m = 0; m < 32; ++m) {
        const float d1m = fmaxf(wsd[m] + wsd[32 + m] + b1[m], 0.f);
        s += d1m * W5[m * 16 + dim];
    }
    float c = fmaxf(s, 0.f) * W6[dim];
    c += __shfl_xor(c, 1);
    c += __shfl_xor(c, 2);
    c += __shfl_xor(c, 4);
    c += __shfl_xor(c, 8);
    if (dim == 0) {
        float o = b7[0] + W7[0] * (b6[0] + c);
        const float* ph = inputs + (size_t)b * (A_DIM * F_DIM) + NAF;
        #pragma unroll
        for (int i = 0; i < NPHYS; ++i) o += W7[i + 1] * ph[i];
        out[(size_t)b * 16] = o;
    }
}

extern "C" void kernel_launch(void* const* d_in, const int* in_sizes, int n_in,
                              void* d_out, int out_size, void* d_ws, size_t ws_size,
                              hipStream_t stream) {
    const float* inputs = (const float*)d_in[0];
    const int*   i_s    = (const int*)d_in[1];
    const float* W_self = (const float*)d_in[2];
    const float* W_nei  = (const float*)d_in[3];
    const float* b_r    = (const float*)d_in[4];
    const float* Wc     = (const float*)d_in[5];
    const float* bc     = (const float*)d_in[6];
    const float* W1     = (const float*)d_in[7];
    const float* b1     = (const float*)d_in[8];
    const float* W5     = (const float*)d_in[9];
    const float* b5     = (const float*)d_in[10];
    const float* W6     = (const float*)d_in[11];
    const float* b6     = (const float*)d_in[12];
    const float* W7     = (const float*)d_in[13];
    const float* b7     = (const float*)d_in[14];
    float* out = (float*)d_out;

    const int B = in_sizes[1];   // 1024
    const size_t wct_bytes = (size_t)C_OUT * KP * sizeof(ushort);   // 49152
    const size_t d1p_bytes = (size_t)B * 64 * sizeof(float);        // 262144
    ushort* wcT = (ushort*)d_ws;
    float*  d1p = (float*)((char*)d_ws + wct_bytes);

    if (ws_size >= wct_bytes + d1p_bytes) {
        wc_prep<<<(C_OUT * KP + 255) / 256, 256, 0, stream>>>(Wc, wcT);
        pggcn_kernel<true, true><<<2 * B, BLOCK, 0, stream>>>(inputs, i_s, W_self,
            W_nei, b_r, Wc, bc, W1, b1, W5, b5, W6, b6, W7, b7, wcT, d1p, out);
        pggcn_combine<<<(B + 15) / 16, 256, 0, stream>>>(inputs, d1p, b1, W5, b5,
            W6, b6, W7, b7, out, B);
    } else if (ws_size >= wct_bytes) {
        wc_prep<<<(C_OUT * KP + 255) / 256, 256, 0, stream>>>(Wc, wcT);
        pggcn_kernel<true, false><<<B, BLOCK, 0, stream>>>(inputs, i_s, W_self,
            W_nei, b_r, Wc, bc, W1, b1, W5, b5, W6, b6, W7, b7, wcT, nullptr, out);
    } else {
        pggcn_kernel<false, false><<<B, BLOCK, 0, stream>>>(inputs, i_s, W_self,
            W_nei, b_r, Wc, bc, W1, b1, W5, b5, W6, b6, W7, b7, nullptr, nullptr, out);
    }
}